// Round 10
// baseline (960.462 us; speedup 1.0000x reference)
//
#include <hip/hip_runtime.h>
#include <hip/hip_bf16.h>

// Problem constants
#define Bb 256
#define Nn_ 17
#define CIN 3
#define HID 64
#define CCH 128        // HEADS*HID
#define Gg 16384       // B*S
#define Ee 81          // 64 edges + 17 self loops
#define LSTM_IN 2176   // 17*128
#define OUT_ 128
#define G4 512         // 4*OUT
#define NCLS 10
#define Tt 64
#define Mg (Gg * Nn_)  // 278528

typedef unsigned short u16;
typedef unsigned int u32;
typedef __attribute__((ext_vector_type(8))) short bf16x8;
typedef __attribute__((ext_vector_type(4))) float f32x4;

__device__ __forceinline__ u16 f2bf(float f) {   // RNE fp32->bf16
    u32 u = __float_as_uint(f);
    u += 0x7fffu + ((u >> 16) & 1u);
    return (u16)(u >> 16);
}
__device__ __forceinline__ float bflo(u32 v) { return __uint_as_float(v << 16); }
__device__ __forceinline__ float bfhi(u32 v) { return __uint_as_float(v & 0xffff0000u); }
__device__ __forceinline__ float bfs(u16 v) { return __uint_as_float(((u32)v) << 16); }

__device__ __forceinline__ void async16(const void* g, void* l) {
    __builtin_amdgcn_global_load_lds((__attribute__((address_space(1))) u32*)g,
                                     (__attribute__((address_space(3))) u32*)l, 16, 0, 0);
}

// ---------------- setup: build src/dst + dst-CSR
__global__ void k_setup(const int* __restrict__ edge_index, int* __restrict__ csr) {
    if (threadIdx.x == 0 && blockIdx.x == 0) {
        int* src = csr;                    // [81]
        int* dst = csr + Ee;               // [81]
        int* off = csr + 2 * Ee;           // [18]
        int* eid = csr + 2 * Ee + Nn_ + 1; // [81]
        for (int e = 0; e < 64; e++) { src[e] = edge_index[e]; dst[e] = edge_index[64 + e]; }
        for (int n = 0; n < Nn_; n++) { src[64 + n] = n; dst[64 + n] = n; }
        int cnt[Nn_];
        for (int n = 0; n < Nn_; n++) cnt[n] = 0;
        for (int e = 0; e < Ee; e++) cnt[dst[e]]++;
        off[0] = 0;
        for (int n = 0; n < Nn_; n++) off[n + 1] = off[n] + cnt[n];
        int pos[Nn_];
        for (int n = 0; n < Nn_; n++) pos[n] = off[n];
        for (int e = 0; e < Ee; e++) eid[pos[dst[e]]++] = e;
    }
}

__global__ void k_convert(const float* __restrict__ in, u16* __restrict__ out, long n) {
    long i = (long)blockIdx.x * 256 + threadIdx.x;
    if (i < n) out[i] = f2bf(in[i]);
}
// 128x128 weight: [k][n] -> bf16 [n][k] (transpose for MFMA B-operand)
__global__ void k_convert_t128(const float* __restrict__ in, u16* __restrict__ out) {
    int i = blockIdx.x * 256 + threadIdx.x;  // over 16384
    int n = i >> 7, k = i & 127;
    out[i] = f2bf(in[k * 128 + n]);
}

// ---------------- GAT layer 0: h[Mg,128]=x@W0 (bf16) + aux[Mg,4]=x@(W0@a) (fp32)
__global__ __launch_bounds__(256) void k_l0(const float* __restrict__ x,
                                            const float* __restrict__ W0,
                                            const float* __restrict__ gas0,
                                            const float* __restrict__ gad0,
                                            u16* __restrict__ h, float* __restrict__ aux) {
    __shared__ float ws[3 * 128];
    __shared__ float w0a[12];   // [ci][j]  j: src_h0,src_h1,dst_h0,dst_h1
    const int t = threadIdx.x;
    for (int i = t; i < 384; i += 256) ws[i] = W0[i];
    __syncthreads();
    if (t < 12) {
        int ci = t >> 2, j = t & 3;
        const float* a = (j < 2) ? gas0 : gad0;
        int hh = j & 1;
        float s = 0.f;
        for (int d = 0; d < HID; d++) s += ws[ci * 128 + hh * 64 + d] * a[hh * 64 + d];
        w0a[t] = s;
    }
    __syncthreads();
    const long row = (long)blockIdx.x * 16 + (t >> 4);
    const int c0 = (t & 15) * 8;
    const float x0 = x[row * 3 + 0], x1 = x[row * 3 + 1], x2 = x[row * 3 + 2];
    union { uint4 u; u16 s[8]; } o;
#pragma unroll
    for (int j = 0; j < 8; j++)
        o.s[j] = f2bf(x0 * ws[c0 + j] + x1 * ws[128 + c0 + j] + x2 * ws[256 + c0 + j]);
    *(uint4*)(h + row * 128 + c0) = o.u;
    if ((t & 15) < 4) {
        int j = t & 3;
        aux[row * 4 + j] = x0 * w0a[j] + x1 * w0a[4 + j] + x2 * w0a[8 + j];
    }
}

// ---------------- GAT MFMA GEMM (in-place): hbuf = hbuf @ W ; aux = fp32 dots vs a_src/a_dst
__global__ __launch_bounds__(256) void k_gemm_gat(u16* __restrict__ HB,
                                                  const u16* __restrict__ Wt,
                                                  const float* __restrict__ a_src,
                                                  const float* __restrict__ a_dst,
                                                  float* __restrict__ aux) {
    __shared__ u16 ldsA[128 * 128];  // 32 KB
    __shared__ float avec[128], dvec[128];
    const int t = threadIdx.x;
    const int w = t >> 6, lane = t & 63;
    const int q = lane >> 4, col = lane & 15;
    const long bm = (long)blockIdx.x * 128;
    const int wm = w * 32;

    if (t < 128) avec[t] = a_src[t];
    else dvec[t - 128] = a_dst[t - 128];

#pragma unroll
    for (int i = 0; i < 8; i++) {
        const int slot = (w * 8 + i) * 64 + lane;
        const int r = slot >> 4, cs = slot & 15;
        const int cg = cs ^ (r & 15);
        async16(HB + (bm + r) * 128 + cg * 8, ldsA + (w * 8 + i) * 512);
    }
    __syncthreads();

    f32x4 acc[2][8] = {};
#pragma unroll
    for (int ks = 0; ks < 4; ks++) {
        const int ck = ks * 4 + q;
        bf16x8 af[2];
#pragma unroll
        for (int mt = 0; mt < 2; mt++) {
            const int m = wm + mt * 16 + col;
            af[mt] = *(const bf16x8*)&ldsA[m * 128 + ((ck ^ (m & 15)) << 3)];
        }
#pragma unroll
        for (int nt = 0; nt < 8; nt++) {
            bf16x8 bf = *(const bf16x8*)&Wt[(nt * 16 + col) * 128 + ck * 8];
            acc[0][nt] = __builtin_amdgcn_mfma_f32_16x16x32_bf16(af[0], bf, acc[0][nt], 0, 0, 0);
            acc[1][nt] = __builtin_amdgcn_mfma_f32_16x16x32_bf16(af[1], bf, acc[1][nt], 0, 0, 0);
        }
    }
    __syncthreads();
#pragma unroll
    for (int mt = 0; mt < 2; mt++) {
#pragma unroll
        for (int nt = 0; nt < 8; nt++) {
            const int cg = nt * 16 + col;
#pragma unroll
            for (int r = 0; r < 4; r++) {
                const long rg = bm + wm + mt * 16 + q * 4 + r;
                HB[rg * 128 + cg] = f2bf(acc[mt][nt][r]);
            }
        }
#pragma unroll
        for (int r = 0; r < 4; r++) {
            float s0 = 0.f, s1 = 0.f, d0 = 0.f, d1 = 0.f;
#pragma unroll
            for (int nt = 0; nt < 4; nt++) {
                const float v = acc[mt][nt][r];
                s0 += v * avec[nt * 16 + col];
                d0 += v * dvec[nt * 16 + col];
            }
#pragma unroll
            for (int nt = 4; nt < 8; nt++) {
                const float v = acc[mt][nt][r];
                s1 += v * avec[nt * 16 + col];
                d1 += v * dvec[nt * 16 + col];
            }
#pragma unroll
            for (int o = 1; o < 16; o <<= 1) {
                s0 += __shfl_xor(s0, o);
                s1 += __shfl_xor(s1, o);
                d0 += __shfl_xor(d0, o);
                d1 += __shfl_xor(d1, o);
            }
            if (col == 0) {
                const long rg = bm + wm + mt * 16 + q * 4 + r;
                aux[rg * 4 + 0] = s0;
                aux[rg * 4 + 1] = s1;
                aux[rg * 4 + 2] = d0;
                aux[rg * 4 + 3] = d1;
            }
        }
    }
}

// ---------------- GAT attention (4 graphs/block)
#define GPB 4
__global__ __launch_bounds__(256) void k_gat_attn(u16* __restrict__ h,
                                                  const float* __restrict__ aux,
                                                  const float* __restrict__ bias,
                                                  const int* __restrict__ csr,
                                                  int relu_flag) {
    __shared__ u32 hs[GPB * Nn_ * 64];
    __shared__ float asd[GPB * Nn_ * 4];     // 272 entries
    __shared__ float ev[GPB][162];
    __shared__ float mS[GPB][34], dS[GPB][34];
    __shared__ float bvec[128];
    __shared__ int srcS[Ee], dstS[Ee], offS[Nn_ + 1], eidS[Ee];
    const int t = threadIdx.x;
    const long g0 = (long)blockIdx.x * GPB;

    if (t < Ee) { srcS[t] = csr[t]; dstS[t] = csr[Ee + t]; eidS[t] = csr[180 + t]; }
    if (t >= 128 && t < 128 + Nn_ + 1) offS[t - 128] = csr[162 + t - 128];
    if (t < 128) bvec[t] = bias[t];
    {
        const u32* hg = (const u32*)h + g0 * 1088;
#pragma unroll
        for (int it = 0; it < 17; it++) hs[t + it * 256] = hg[t + it * 256];
        const float* ag = aux + g0 * 68;
        // 272 entries > 256 threads: full coverage loop (r8 bugfix)
        for (int i = t; i < GPB * Nn_ * 4; i += 256) asd[i] = ag[i];
    }
    __syncthreads();
    for (int i = t; i < GPB * 162; i += 256) {
        const int g = i / 162, rem = i % 162, e = rem >> 1, hh = rem & 1;
        float v = asd[(g * Nn_ + srcS[e]) * 4 + hh] + asd[(g * Nn_ + dstS[e]) * 4 + 2 + hh];
        ev[g][rem] = (v > 0.f) ? v : 0.2f * v;
    }
    __syncthreads();
    if (t < GPB * 34) {
        const int g = t / 34, rem = t % 34, n = rem >> 1, hh = rem & 1;
        const int p0 = offS[n], p1 = offS[n + 1];
        float m = -1e30f;
        for (int p = p0; p < p1; p++) m = fmaxf(m, ev[g][eidS[p] * 2 + hh]);
        float den = 0.f;
        for (int p = p0; p < p1; p++) den += expf(ev[g][eidS[p] * 2 + hh] - m);
        mS[g][rem] = m;
        dS[g][rem] = den;
    }
    __syncthreads();
    for (int i = t; i < GPB * 162; i += 256) {
        const int g = i / 162, rem = i % 162, e = rem >> 1, hh = rem & 1;
        const int n = dstS[e];
        ev[g][rem] = expf(ev[g][rem] - mS[g][n * 2 + hh]) / (dS[g][n * 2 + hh] + 1e-16f);
    }
    __syncthreads();
    u32* hg = (u32*)h + g0 * 1088;
#pragma unroll
    for (int it = 0; it < 17; it++) {
        const int i = t + it * 256;
        const int gg = i / 1088, rr = i % 1088;
        const int n = rr >> 6, cp = rr & 63, hh = cp >> 5;
        const int p0 = offS[n], p1 = offS[n + 1];
        float a0 = 0.f, a1 = 0.f;
        for (int p = p0; p < p1; p++) {
            const int e = eidS[p];
            const u32 hv = hs[(gg * Nn_ + srcS[e]) * 64 + cp];
            const float al = ev[gg][e * 2 + hh];
            a0 += al * bflo(hv);
            a1 += al * bfhi(hv);
        }
        a0 += bvec[cp * 2];
        a1 += bvec[cp * 2 + 1];
        if (relu_flag) { a0 = fmaxf(a0, 0.f); a1 = fmaxf(a1, 0.f); }
        hg[gg * 1088 + n * 64 + cp] = (u32)f2bf(a0) | ((u32)f2bf(a1) << 16);
    }
}

// ---------------- bf16 MFMA GEMM: C[M,ldc] = A[M,K]bf16 @ Bt[N,K]bf16^T + b1[n]+b2[n] (fp32)
__global__ __launch_bounds__(256) void k_gemm_mfma(const u16* __restrict__ A,
                                                   const u16* __restrict__ Bt,
                                                   float* __restrict__ Cm,
                                                   const float* __restrict__ b1,
                                                   const float* __restrict__ b2,
                                                   int K, int ldc) {
    __shared__ u16 ldsA[128 * 64];
    __shared__ u16 ldsB[128 * 64];
    const int w = threadIdx.x >> 6;
    const int lane = threadIdx.x & 63;
    const long bm = (long)blockIdx.x * 128;
    const int bn = blockIdx.y * 128;
    const int wm = (w & 1) * 64, wn = (w >> 1) * 64;
    const int q = lane >> 4, col = lane & 15;
    f32x4 acc[4][4] = {};
    for (int k0 = 0; k0 < K; k0 += 64) {
#pragma unroll
        for (int i = 0; i < 4; i++) {
            const int slot = (w * 4 + i) * 64 + lane;
            const int r = slot >> 3, cs = slot & 7;
            const int cg = cs ^ (r & 7);
            async16(A + (bm + r) * (long)K + k0 + cg * 8, ldsA + (w * 4 + i) * 512);
            async16(Bt + (long)(bn + r) * K + k0 + cg * 8, ldsB + (w * 4 + i) * 512);
        }
        __syncthreads();
#pragma unroll
        for (int kk = 0; kk < 2; kk++) {
            bf16x8 af[4], bfr[4];
#pragma unroll
            for (int mt = 0; mt < 4; mt++) {
                const int m = wm + mt * 16 + col;
                const int cs = (kk * 4 + q) ^ (m & 7);
                af[mt] = *(const bf16x8*)&ldsA[m * 64 + cs * 8];
            }
#pragma unroll
            for (int nt = 0; nt < 4; nt++) {
                const int n = wn + nt * 16 + col;
                const int cs = (kk * 4 + q) ^ (n & 7);
                bfr[nt] = *(const bf16x8*)&ldsB[n * 64 + cs * 8];
            }
#pragma unroll
            for (int mt = 0; mt < 4; mt++)
#pragma unroll
                for (int nt = 0; nt < 4; nt++)
                    acc[mt][nt] = __builtin_amdgcn_mfma_f32_16x16x32_bf16(af[mt], bfr[nt], acc[mt][nt], 0, 0, 0);
        }
        __syncthreads();
    }
#pragma unroll
    for (int mt = 0; mt < 4; mt++)
#pragma unroll
        for (int nt = 0; nt < 4; nt++) {
            const int cg = bn + wn + nt * 16 + col;
            const float bb = b1[cg] + b2[cg];
#pragma unroll
            for (int r = 0; r < 4; r++) {
                const long rg = bm + wm + mt * 16 + q * 4 + r;
                Cm[rg * ldc + cg] = acc[mt][nt][r] + bb;
            }
        }
}

// ================ MFMA LSTM recurrence: 128 blocks x 2 batch rows ================
// gates(t) = XW[t] (prefetched fp32, biases included) + h(t-1) @ whh^T via MFMA.
// h enters MFMA as hi/lo split-bf16 (2 passes -> ~fp32 accuracy for the recurrent matmul);
// whh is single bf16 (static weight quantization, same class as wih0-bf16 which passes).
// whh B-frags live in VGPRs for the whole loop (128 VGPRs) -- no per-step weight traffic
// (round-8 lesson: per-step global B-fetch kills it; round-9 lesson: VGPR_Count=80 proved
// the scalar k_lstm was reloading whh from L1/L2 every step + 256 LDS broadcasts/step).
// Wave w owns j-tiles {w, w+4}; all 4 gate tiles of a j-tile in the same lane -> cell math
// is lane-local. Only rows 0..1 are real; MFMA rows 2..15 are zeros riding along.
template <int OBF16>
__global__ __launch_bounds__(256, 1) void k_lstm_mfma(const float* __restrict__ XW,
                                                      const u16* __restrict__ whhb,
                                                      void* __restrict__ hseq) {
    __shared__ __align__(16) u16 hHi[16 * 136];   // [batch-row][k=j], stride 136 (bank-spread)
    __shared__ __align__(16) u16 hLo[16 * 136];
    const int t_ = threadIdx.x;
    const int w = t_ >> 6, lane = t_ & 63, q = lane >> 4, col = lane & 15;
    const long b0 = (long)blockIdx.x * 2;   // 2 batch rows per block

    bf16x8 wf[2][4][4];   // [jj][gate][ks] B-frags, loop-invariant
#pragma unroll
    for (int jj = 0; jj < 2; jj++)
#pragma unroll
        for (int a = 0; a < 4; a++) {
            const int n = a * 128 + (w + 4 * jj) * 16 + col;
#pragma unroll
            for (int ks = 0; ks < 4; ks++)
                wf[jj][a][ks] = *(const bf16x8*)&whhb[n * 128 + ks * 32 + q * 8];
        }
    for (int i = t_; i < 16 * 136; i += 256) { hHi[i] = 0; hLo[i] = 0; }
    float cst[2][2] = {};   // c-state for rows 0..1 (q==0 lanes), [jj][r]
    f32x4 nxt[2][4];
#pragma unroll
    for (int jj = 0; jj < 2; jj++)
#pragma unroll
        for (int a = 0; a < 4; a++) {
            const int n = a * 128 + (w + 4 * jj) * 16 + col;
#pragma unroll
            for (int r = 0; r < 4; r++) {
                const long br = (b0 + q * 4 + r < Bb) ? (b0 + q * 4 + r) : (Bb - 1);
                nxt[jj][a][r] = XW[(br * Tt + 0) * G4 + n];
            }
        }
    __syncthreads();

    for (int t = 0; t < Tt; t++) {
        f32x4 acc[2][4];
#pragma unroll
        for (int jj = 0; jj < 2; jj++)
#pragma unroll
            for (int a = 0; a < 4; a++) acc[jj][a] = nxt[jj][a];
#pragma unroll
        for (int ks = 0; ks < 4; ks++) {
            bf16x8 ah = *(const bf16x8*)&hHi[col * 136 + ks * 32 + q * 8];
            bf16x8 al = *(const bf16x8*)&hLo[col * 136 + ks * 32 + q * 8];
#pragma unroll
            for (int jj = 0; jj < 2; jj++)
#pragma unroll
                for (int a = 0; a < 4; a++) {
                    acc[jj][a] = __builtin_amdgcn_mfma_f32_16x16x32_bf16(ah, wf[jj][a][ks], acc[jj][a], 0, 0, 0);
                    acc[jj][a] = __builtin_amdgcn_mfma_f32_16x16x32_bf16(al, wf[jj][a][ks], acc[jj][a], 0, 0, 0);
                }
        }
        // prefetch XW for t+1 (register-dest loads stay in flight across compute)
        const int tn = (t < Tt - 1) ? t + 1 : Tt - 1;
#pragma unroll
        for (int jj = 0; jj < 2; jj++)
#pragma unroll
            for (int a = 0; a < 4; a++) {
                const int n = a * 128 + (w + 4 * jj) * 16 + col;
#pragma unroll
                for (int r = 0; r < 4; r++) {
                    const long br = (b0 + q * 4 + r < Bb) ? (b0 + q * 4 + r) : (Bb - 1);
                    nxt[jj][a][r] = XW[(br * Tt + tn) * G4 + n];
                }
            }
        __syncthreads();   // all h reads done before h writes
        if (q == 0) {
#pragma unroll
            for (int jj = 0; jj < 2; jj++) {
                const int j = (w + 4 * jj) * 16 + col;
#pragma unroll
                for (int r = 0; r < 2; r++) {
                    const float gi = acc[jj][0][r], gf = acc[jj][1][r];
                    const float gg = acc[jj][2][r], go = acc[jj][3][r];
                    const float si = 1.f / (1.f + expf(-gi));
                    const float sf = 1.f / (1.f + expf(-gf));
                    const float so = 1.f / (1.f + expf(-go));
                    const float c = sf * cst[jj][r] + si * tanhf(gg);
                    cst[jj][r] = c;
                    const float hh = so * tanhf(c);
                    const u16 hi = f2bf(hh);
                    hHi[r * 136 + j] = hi;
                    hLo[r * 136 + j] = f2bf(hh - bfs(hi));
                    const long idx = ((b0 + r) * Tt + t) * OUT_ + j;
                    if (OBF16) ((u16*)hseq)[idx] = hi;
                    else       ((float*)hseq)[idx] = hh;
                }
            }
        }
        __syncthreads();   // h(t) visible before next step's reads
    }
}

// ---------------- attention pooling + FC
__global__ __launch_bounds__(64) void k_attn_fc(const float* __restrict__ h2,
                                                const float* __restrict__ attn_w,
                                                const float* __restrict__ attn_b,
                                                const float* __restrict__ fc_w,
                                                const float* __restrict__ fc_b,
                                                float* __restrict__ out) {
    const int b = blockIdx.x, t = threadIdx.x;
    __shared__ float aw[Tt];
    __shared__ float ctx[OUT_];
    const float* hb = h2 + (long)b * Tt * OUT_;
    float acc = 0.f;
    for (int d = 0; d < OUT_; d++) acc += hb[t * OUT_ + d] * attn_w[d];
    float sc = tanhf(acc + attn_b[0]);
    float m = sc;
#pragma unroll
    for (int o = 32; o > 0; o >>= 1) m = fmaxf(m, __shfl_xor(m, o));
    float ex = expf(sc - m);
    float sum = ex;
#pragma unroll
    for (int o = 32; o > 0; o >>= 1) sum += __shfl_xor(sum, o);
    aw[t] = ex / sum;
    __syncthreads();
    for (int d = t; d < OUT_; d += 64) {
        float c = 0.f;
        for (int tt = 0; tt < Tt; tt++) c += aw[tt] * hb[tt * OUT_ + d];
        ctx[d] = c;
    }
    __syncthreads();
    if (t < NCLS) {
        float o = fc_b[t];
        for (int d = 0; d < OUT_; d++) o += ctx[d] * fc_w[t * OUT_ + d];
        out[b * NCLS + t] = o;
    }
}

extern "C" void kernel_launch(void* const* d_in, const int* in_sizes, int n_in,
                              void* d_out, int out_size, void* d_ws, size_t ws_size,
                              hipStream_t stream) {
    const float* x          = (const float*)d_in[0];
    const int*   edge_index = (const int*)d_in[1];
    const float* gw[4]  = {(const float*)d_in[2], (const float*)d_in[6], (const float*)d_in[10], (const float*)d_in[14]};
    const float* gas[4] = {(const float*)d_in[3], (const float*)d_in[7], (const float*)d_in[11], (const float*)d_in[15]};
    const float* gad[4] = {(const float*)d_in[4], (const float*)d_in[8], (const float*)d_in[12], (const float*)d_in[16]};
    const float* gb[4]  = {(const float*)d_in[5], (const float*)d_in[9], (const float*)d_in[13], (const float*)d_in[17]};
    const float* wih0 = (const float*)d_in[18];
    const float* whh0 = (const float*)d_in[19];
    const float* bih0 = (const float*)d_in[20];
    const float* bhh0 = (const float*)d_in[21];
    const float* wih1 = (const float*)d_in[22];
    const float* whh1 = (const float*)d_in[23];
    const float* bih1 = (const float*)d_in[24];
    const float* bhh1 = (const float*)d_in[25];
    const float* attn_w = (const float*)d_in[26];
    const float* attn_b = (const float*)d_in[27];
    const float* fc_w   = (const float*)d_in[28];
    const float* fc_b   = (const float*)d_in[29];
    float* out = (float*)d_out;
    char* p = (char*)d_ws;

    // Workspace (~158.2 MB; 176.2 MB proven OK in round 2)
    u16*   hbuf  = (u16*)(p + 0L);              // 71,303,168 B
    float* aux   = (float*)(p + 71303168L);     //  4,456,448 B
    float* XW0   = (float*)(p + 75759616L);     // 33,554,432 B
    float* XW1   = (float*)(p + 109314048L);    // 33,554,432 B
    float* h2s   = (float*)(p + 142868480L);    //  8,388,608 B
    u16*   h1s   = (u16*)(p + 151257088L);      //  4,194,304 B
    u16*   wih0b = (u16*)(p + 155451392L);      //  2,228,224 B
    u16*   wih1b = (u16*)(p + 157679616L);      //    131,072 B
    u16*   whh0b = (u16*)(p + 157810688L);      //    131,072 B
    u16*   whh1b = (u16*)(p + 157941760L);      //    131,072 B
    u16*   wt1   = (u16*)(p + 158072832L);      //     32,768 B (x3)
    u16*   wt2   = (u16*)(p + 158105600L);
    u16*   wt3   = (u16*)(p + 158138368L);
    int*   csr   = (int*)(p + 158171136L);      //      1,044 B

    k_setup<<<1, 1, 0, stream>>>(edge_index, csr);
    k_convert_t128<<<64, 256, 0, stream>>>(gw[1], wt1);
    k_convert_t128<<<64, 256, 0, stream>>>(gw[2], wt2);
    k_convert_t128<<<64, 256, 0, stream>>>(gw[3], wt3);
    k_convert<<<(512 * 2176 + 255) / 256, 256, 0, stream>>>(wih0, wih0b, 512L * 2176);
    k_convert<<<256, 256, 0, stream>>>(wih1, wih1b, 512L * 128);
    k_convert<<<256, 256, 0, stream>>>(whh0, whh0b, 512L * 128);
    k_convert<<<256, 256, 0, stream>>>(whh1, whh1b, 512L * 128);

    // GAT layer 0 projection (+fp32 attn dots) then attention
    k_l0<<<Mg / 16, 256, 0, stream>>>(x, gw[0], gas[0], gad[0], hbuf, aux);
    k_gat_attn<<<Gg / GPB, 256, 0, stream>>>(hbuf, aux, gb[0], csr, 1);
    // layers 1..3: in-place MFMA GEMM with fp32 dot epilogue, then attention
    k_gemm_gat<<<Mg / 128, 256, 0, stream>>>(hbuf, wt1, gas[1], gad[1], aux);
    k_gat_attn<<<Gg / GPB, 256, 0, stream>>>(hbuf, aux, gb[1], csr, 0);
    k_gemm_gat<<<Mg / 128, 256, 0, stream>>>(hbuf, wt2, gas[2], gad[2], aux);
    k_gat_attn<<<Gg / GPB, 256, 0, stream>>>(hbuf, aux, gb[2], csr, 1);
    k_gemm_gat<<<Mg / 128, 256, 0, stream>>>(hbuf, wt3, gas[3], gad[3], aux);
    k_gat_attn<<<Gg / GPB, 256, 0, stream>>>(hbuf, aux, gb[3], csr, 0);

    // LSTM layer 0: input GEMM (hbuf == lstm_in [16384,2176] bf16) + MFMA recurrence
    k_gemm_mfma<<<dim3(Gg / 128, 4), 256, 0, stream>>>(hbuf, wih0b, XW0, bih0, bhh0, LSTM_IN, G4);
    k_lstm_mfma<1><<<Bb / 2, 256, 0, stream>>>(XW0, whh0b, h1s);
    // LSTM layer 1
    k_gemm_mfma<<<dim3(Gg / 128, 4), 256, 0, stream>>>(h1s, wih1b, XW1, bih1, bhh1, OUT_, G4);
    k_lstm_mfma<0><<<Bb / 2, 256, 0, stream>>>(XW1, whh1b, h2s);

    k_attn_fc<<<Bb, 64, 0, stream>>>(h2s, attn_w, attn_b, fc_w, fc_b, out);
}

// Round 11
// 936.022 us; speedup vs baseline: 1.0261x; 1.0261x over previous
//
#include <hip/hip_runtime.h>
#include <hip/hip_bf16.h>

// Problem constants
#define Bb 256
#define Nn_ 17
#define CIN 3
#define HID 64
#define CCH 128        // HEADS*HID
#define Gg 16384       // B*S
#define Ee 81          // 64 edges + 17 self loops
#define LSTM_IN 2176   // 17*128
#define OUT_ 128
#define G4 512         // 4*OUT
#define NCLS 10
#define Tt 64
#define Mg (Gg * Nn_)  // 278528

typedef unsigned short u16;
typedef unsigned int u32;
typedef __attribute__((ext_vector_type(8))) short bf16x8;
typedef __attribute__((ext_vector_type(4))) float f32x4;

__device__ __forceinline__ u16 f2bf(float f) {   // RNE fp32->bf16
    u32 u = __float_as_uint(f);
    u += 0x7fffu + ((u >> 16) & 1u);
    return (u16)(u >> 16);
}
__device__ __forceinline__ float bflo(u32 v) { return __uint_as_float(v << 16); }
__device__ __forceinline__ float bfhi(u32 v) { return __uint_as_float(v & 0xffff0000u); }
__device__ __forceinline__ float bfs(u16 v) { return __uint_as_float(((u32)v) << 16); }

__device__ __forceinline__ void async16(const void* g, void* l) {
    __builtin_amdgcn_global_load_lds((__attribute__((address_space(1))) u32*)g,
                                     (__attribute__((address_space(3))) u32*)l, 16, 0, 0);
}

// ---------------- setup: build src/dst + dst-CSR
__global__ void k_setup(const int* __restrict__ edge_index, int* __restrict__ csr) {
    if (threadIdx.x == 0 && blockIdx.x == 0) {
        int* src = csr;                    // [81]
        int* dst = csr + Ee;               // [81]
        int* off = csr + 2 * Ee;           // [18]
        int* eid = csr + 2 * Ee + Nn_ + 1; // [81]
        for (int e = 0; e < 64; e++) { src[e] = edge_index[e]; dst[e] = edge_index[64 + e]; }
        for (int n = 0; n < Nn_; n++) { src[64 + n] = n; dst[64 + n] = n; }
        int cnt[Nn_];
        for (int n = 0; n < Nn_; n++) cnt[n] = 0;
        for (int e = 0; e < Ee; e++) cnt[dst[e]]++;
        off[0] = 0;
        for (int n = 0; n < Nn_; n++) off[n + 1] = off[n] + cnt[n];
        int pos[Nn_];
        for (int n = 0; n < Nn_; n++) pos[n] = off[n];
        for (int e = 0; e < Ee; e++) eid[pos[dst[e]]++] = e;
    }
}

__global__ void k_convert(const float* __restrict__ in, u16* __restrict__ out, long n) {
    long i = (long)blockIdx.x * 256 + threadIdx.x;
    if (i < n) out[i] = f2bf(in[i]);
}
// 128x128 weight: [k][n] -> bf16 [n][k] (transpose for MFMA B-operand)
__global__ void k_convert_t128(const float* __restrict__ in, u16* __restrict__ out) {
    int i = blockIdx.x * 256 + threadIdx.x;  // over 16384
    int n = i >> 7, k = i & 127;
    out[i] = f2bf(in[k * 128 + n]);
}

// ---------------- GAT layer 0: h[Mg,128]=x@W0 (bf16) + aux[Mg,4]=x@(W0@a) (fp32)
__global__ __launch_bounds__(256) void k_l0(const float* __restrict__ x,
                                            const float* __restrict__ W0,
                                            const float* __restrict__ gas0,
                                            const float* __restrict__ gad0,
                                            u16* __restrict__ h, float* __restrict__ aux) {
    __shared__ float ws[3 * 128];
    __shared__ float w0a[12];   // [ci][j]  j: src_h0,src_h1,dst_h0,dst_h1
    const int t = threadIdx.x;
    for (int i = t; i < 384; i += 256) ws[i] = W0[i];
    __syncthreads();
    if (t < 12) {
        int ci = t >> 2, j = t & 3;
        const float* a = (j < 2) ? gas0 : gad0;
        int hh = j & 1;
        float s = 0.f;
        for (int d = 0; d < HID; d++) s += ws[ci * 128 + hh * 64 + d] * a[hh * 64 + d];
        w0a[t] = s;
    }
    __syncthreads();
    const long row = (long)blockIdx.x * 16 + (t >> 4);
    const int c0 = (t & 15) * 8;
    const float x0 = x[row * 3 + 0], x1 = x[row * 3 + 1], x2 = x[row * 3 + 2];
    union { uint4 u; u16 s[8]; } o;
#pragma unroll
    for (int j = 0; j < 8; j++)
        o.s[j] = f2bf(x0 * ws[c0 + j] + x1 * ws[128 + c0 + j] + x2 * ws[256 + c0 + j]);
    *(uint4*)(h + row * 128 + c0) = o.u;
    if ((t & 15) < 4) {
        int j = t & 3;
        aux[row * 4 + j] = x0 * w0a[j] + x1 * w0a[4 + j] + x2 * w0a[8 + j];
    }
}

// ---------------- GAT MFMA GEMM (in-place): hbuf = hbuf @ W ; aux = fp32 dots vs a_src/a_dst
__global__ __launch_bounds__(256) void k_gemm_gat(u16* __restrict__ HB,
                                                  const u16* __restrict__ Wt,
                                                  const float* __restrict__ a_src,
                                                  const float* __restrict__ a_dst,
                                                  float* __restrict__ aux) {
    __shared__ u16 ldsA[128 * 128];  // 32 KB
    __shared__ float avec[128], dvec[128];
    const int t = threadIdx.x;
    const int w = t >> 6, lane = t & 63;
    const int q = lane >> 4, col = lane & 15;
    const long bm = (long)blockIdx.x * 128;
    const int wm = w * 32;

    if (t < 128) avec[t] = a_src[t];
    else dvec[t - 128] = a_dst[t - 128];

#pragma unroll
    for (int i = 0; i < 8; i++) {
        const int slot = (w * 8 + i) * 64 + lane;
        const int r = slot >> 4, cs = slot & 15;
        const int cg = cs ^ (r & 15);
        async16(HB + (bm + r) * 128 + cg * 8, ldsA + (w * 8 + i) * 512);
    }
    __syncthreads();

    f32x4 acc[2][8] = {};
#pragma unroll
    for (int ks = 0; ks < 4; ks++) {
        const int ck = ks * 4 + q;
        bf16x8 af[2];
#pragma unroll
        for (int mt = 0; mt < 2; mt++) {
            const int m = wm + mt * 16 + col;
            af[mt] = *(const bf16x8*)&ldsA[m * 128 + ((ck ^ (m & 15)) << 3)];
        }
#pragma unroll
        for (int nt = 0; nt < 8; nt++) {
            bf16x8 bf = *(const bf16x8*)&Wt[(nt * 16 + col) * 128 + ck * 8];
            acc[0][nt] = __builtin_amdgcn_mfma_f32_16x16x32_bf16(af[0], bf, acc[0][nt], 0, 0, 0);
            acc[1][nt] = __builtin_amdgcn_mfma_f32_16x16x32_bf16(af[1], bf, acc[1][nt], 0, 0, 0);
        }
    }
    __syncthreads();
#pragma unroll
    for (int mt = 0; mt < 2; mt++) {
#pragma unroll
        for (int nt = 0; nt < 8; nt++) {
            const int cg = nt * 16 + col;
#pragma unroll
            for (int r = 0; r < 4; r++) {
                const long rg = bm + wm + mt * 16 + q * 4 + r;
                HB[rg * 128 + cg] = f2bf(acc[mt][nt][r]);
            }
        }
#pragma unroll
        for (int r = 0; r < 4; r++) {
            float s0 = 0.f, s1 = 0.f, d0 = 0.f, d1 = 0.f;
#pragma unroll
            for (int nt = 0; nt < 4; nt++) {
                const float v = acc[mt][nt][r];
                s0 += v * avec[nt * 16 + col];
                d0 += v * dvec[nt * 16 + col];
            }
#pragma unroll
            for (int nt = 4; nt < 8; nt++) {
                const float v = acc[mt][nt][r];
                s1 += v * avec[nt * 16 + col];
                d1 += v * dvec[nt * 16 + col];
            }
#pragma unroll
            for (int o = 1; o < 16; o <<= 1) {
                s0 += __shfl_xor(s0, o);
                s1 += __shfl_xor(s1, o);
                d0 += __shfl_xor(d0, o);
                d1 += __shfl_xor(d1, o);
            }
            if (col == 0) {
                const long rg = bm + wm + mt * 16 + q * 4 + r;
                aux[rg * 4 + 0] = s0;
                aux[rg * 4 + 1] = s1;
                aux[rg * 4 + 2] = d0;
                aux[rg * 4 + 3] = d1;
            }
        }
    }
}

// ---------------- GAT attention (4 graphs/block)
#define GPB 4
__global__ __launch_bounds__(256) void k_gat_attn(u16* __restrict__ h,
                                                  const float* __restrict__ aux,
                                                  const float* __restrict__ bias,
                                                  const int* __restrict__ csr,
                                                  int relu_flag) {
    __shared__ u32 hs[GPB * Nn_ * 64];
    __shared__ float asd[GPB * Nn_ * 4];     // 272 entries
    __shared__ float ev[GPB][162];
    __shared__ float mS[GPB][34], dS[GPB][34];
    __shared__ float bvec[128];
    __shared__ int srcS[Ee], dstS[Ee], offS[Nn_ + 1], eidS[Ee];
    const int t = threadIdx.x;
    const long g0 = (long)blockIdx.x * GPB;

    if (t < Ee) { srcS[t] = csr[t]; dstS[t] = csr[Ee + t]; eidS[t] = csr[180 + t]; }
    if (t >= 128 && t < 128 + Nn_ + 1) offS[t - 128] = csr[162 + t - 128];
    if (t < 128) bvec[t] = bias[t];
    {
        const u32* hg = (const u32*)h + g0 * 1088;
#pragma unroll
        for (int it = 0; it < 17; it++) hs[t + it * 256] = hg[t + it * 256];
        const float* ag = aux + g0 * 68;
        // 272 entries > 256 threads: full coverage loop (r8 bugfix)
        for (int i = t; i < GPB * Nn_ * 4; i += 256) asd[i] = ag[i];
    }
    __syncthreads();
    for (int i = t; i < GPB * 162; i += 256) {
        const int g = i / 162, rem = i % 162, e = rem >> 1, hh = rem & 1;
        float v = asd[(g * Nn_ + srcS[e]) * 4 + hh] + asd[(g * Nn_ + dstS[e]) * 4 + 2 + hh];
        ev[g][rem] = (v > 0.f) ? v : 0.2f * v;
    }
    __syncthreads();
    if (t < GPB * 34) {
        const int g = t / 34, rem = t % 34, n = rem >> 1, hh = rem & 1;
        const int p0 = offS[n], p1 = offS[n + 1];
        float m = -1e30f;
        for (int p = p0; p < p1; p++) m = fmaxf(m, ev[g][eidS[p] * 2 + hh]);
        float den = 0.f;
        for (int p = p0; p < p1; p++) den += expf(ev[g][eidS[p] * 2 + hh] - m);
        mS[g][rem] = m;
        dS[g][rem] = den;
    }
    __syncthreads();
    for (int i = t; i < GPB * 162; i += 256) {
        const int g = i / 162, rem = i % 162, e = rem >> 1, hh = rem & 1;
        const int n = dstS[e];
        ev[g][rem] = expf(ev[g][rem] - mS[g][n * 2 + hh]) / (dS[g][n * 2 + hh] + 1e-16f);
    }
    __syncthreads();
    u32* hg = (u32*)h + g0 * 1088;
#pragma unroll
    for (int it = 0; it < 17; it++) {
        const int i = t + it * 256;
        const int gg = i / 1088, rr = i % 1088;
        const int n = rr >> 6, cp = rr & 63, hh = cp >> 5;
        const int p0 = offS[n], p1 = offS[n + 1];
        float a0 = 0.f, a1 = 0.f;
        for (int p = p0; p < p1; p++) {
            const int e = eidS[p];
            const u32 hv = hs[(gg * Nn_ + srcS[e]) * 64 + cp];
            const float al = ev[gg][e * 2 + hh];
            a0 += al * bflo(hv);
            a1 += al * bfhi(hv);
        }
        a0 += bvec[cp * 2];
        a1 += bvec[cp * 2 + 1];
        if (relu_flag) { a0 = fmaxf(a0, 0.f); a1 = fmaxf(a1, 0.f); }
        hg[gg * 1088 + n * 64 + cp] = (u32)f2bf(a0) | ((u32)f2bf(a1) << 16);
    }
}

// ---------------- bf16 MFMA GEMM: C[M,ldc] = A[M,K]bf16 @ Bt[N,K]bf16^T + b1[n]+b2[n] (fp32)
__global__ __launch_bounds__(256) void k_gemm_mfma(const u16* __restrict__ A,
                                                   const u16* __restrict__ Bt,
                                                   float* __restrict__ Cm,
                                                   const float* __restrict__ b1,
                                                   const float* __restrict__ b2,
                                                   int K, int ldc) {
    __shared__ u16 ldsA[128 * 64];
    __shared__ u16 ldsB[128 * 64];
    const int w = threadIdx.x >> 6;
    const int lane = threadIdx.x & 63;
    const long bm = (long)blockIdx.x * 128;
    const int bn = blockIdx.y * 128;
    const int wm = (w & 1) * 64, wn = (w >> 1) * 64;
    const int q = lane >> 4, col = lane & 15;
    f32x4 acc[4][4] = {};
    for (int k0 = 0; k0 < K; k0 += 64) {
#pragma unroll
        for (int i = 0; i < 4; i++) {
            const int slot = (w * 4 + i) * 64 + lane;
            const int r = slot >> 3, cs = slot & 7;
            const int cg = cs ^ (r & 7);
            async16(A + (bm + r) * (long)K + k0 + cg * 8, ldsA + (w * 4 + i) * 512);
            async16(Bt + (long)(bn + r) * K + k0 + cg * 8, ldsB + (w * 4 + i) * 512);
        }
        __syncthreads();
#pragma unroll
        for (int kk = 0; kk < 2; kk++) {
            bf16x8 af[4], bfr[4];
#pragma unroll
            for (int mt = 0; mt < 4; mt++) {
                const int m = wm + mt * 16 + col;
                const int cs = (kk * 4 + q) ^ (m & 7);
                af[mt] = *(const bf16x8*)&ldsA[m * 64 + cs * 8];
            }
#pragma unroll
            for (int nt = 0; nt < 4; nt++) {
                const int n = wn + nt * 16 + col;
                const int cs = (kk * 4 + q) ^ (n & 7);
                bfr[nt] = *(const bf16x8*)&ldsB[n * 64 + cs * 8];
            }
#pragma unroll
            for (int mt = 0; mt < 4; mt++)
#pragma unroll
                for (int nt = 0; nt < 4; nt++)
                    acc[mt][nt] = __builtin_amdgcn_mfma_f32_16x16x32_bf16(af[mt], bfr[nt], acc[mt][nt], 0, 0, 0);
        }
        __syncthreads();
    }
#pragma unroll
    for (int mt = 0; mt < 4; mt++)
#pragma unroll
        for (int nt = 0; nt < 4; nt++) {
            const int cg = bn + wn + nt * 16 + col;
            const float bb = b1[cg] + b2[cg];
#pragma unroll
            for (int r = 0; r < 4; r++) {
                const long rg = bm + wm + mt * 16 + q * 4 + r;
                Cm[rg * ldc + cg] = acc[mt][nt][r] + bb;
            }
        }
}

// ================ MFMA LSTM recurrence: 128 blocks x 2 batch rows ================
// gates(t) = XW[t] (prefetched fp32, biases included) + h(t-1) @ whh^T via MFMA.
// h enters MFMA as hi/lo split-bf16 (2 passes -> ~fp32 accuracy); whh single bf16.
// whh B-frags live in VGPRs for the whole loop. R10 FIX: XW is loaded ONLY for the
// block's 2 real batch rows (q==0, r<2); MFMA pad rows 2..15 get 0.0f. The r9 version
// loaded XW for all 16 rows -> 8x over-fetch, FETCH_SIZE=128MB/dispatch, 166us at
// 814 GB/s pure HBM streaming. This cuts FETCH to ~34MB (XW read exactly once).
template <int OBF16>
__global__ __launch_bounds__(256, 1) void k_lstm_mfma(const float* __restrict__ XW,
                                                      const u16* __restrict__ whhb,
                                                      void* __restrict__ hseq) {
    __shared__ __align__(16) u16 hHi[16 * 136];   // [batch-row][k=j], stride 136 (bank-spread)
    __shared__ __align__(16) u16 hLo[16 * 136];
    const int t_ = threadIdx.x;
    const int w = t_ >> 6, lane = t_ & 63, q = lane >> 4, col = lane & 15;
    const long b0 = (long)blockIdx.x * 2;   // 2 batch rows per block

    bf16x8 wf[2][4][4];   // [jj][gate][ks] B-frags, loop-invariant
#pragma unroll
    for (int jj = 0; jj < 2; jj++)
#pragma unroll
        for (int a = 0; a < 4; a++) {
            const int n = a * 128 + (w + 4 * jj) * 16 + col;
#pragma unroll
            for (int ks = 0; ks < 4; ks++)
                wf[jj][a][ks] = *(const bf16x8*)&whhb[n * 128 + ks * 32 + q * 8];
        }
    for (int i = t_; i < 16 * 136; i += 256) { hHi[i] = 0; hLo[i] = 0; }
    float cst[2][2] = {};   // c-state for rows 0..1 (q==0 lanes), [jj][r]
    float nxt[2][4][2];     // [jj][gate][r] -- only q==0, r<2 real
#pragma unroll
    for (int jj = 0; jj < 2; jj++)
#pragma unroll
        for (int a = 0; a < 4; a++) {
            const int n = a * 128 + (w + 4 * jj) * 16 + col;
#pragma unroll
            for (int r = 0; r < 2; r++)
                nxt[jj][a][r] = (q == 0) ? XW[((b0 + r) * Tt + 0) * G4 + n] : 0.f;
        }
    __syncthreads();

    for (int t = 0; t < Tt; t++) {
        f32x4 acc[2][4];
#pragma unroll
        for (int jj = 0; jj < 2; jj++)
#pragma unroll
            for (int a = 0; a < 4; a++) {
                acc[jj][a][0] = nxt[jj][a][0];
                acc[jj][a][1] = nxt[jj][a][1];
                acc[jj][a][2] = 0.f;
                acc[jj][a][3] = 0.f;
            }
#pragma unroll
        for (int ks = 0; ks < 4; ks++) {
            bf16x8 ah = *(const bf16x8*)&hHi[col * 136 + ks * 32 + q * 8];
            bf16x8 al = *(const bf16x8*)&hLo[col * 136 + ks * 32 + q * 8];
#pragma unroll
            for (int jj = 0; jj < 2; jj++)
#pragma unroll
                for (int a = 0; a < 4; a++) {
                    acc[jj][a] = __builtin_amdgcn_mfma_f32_16x16x32_bf16(ah, wf[jj][a][ks], acc[jj][a], 0, 0, 0);
                    acc[jj][a] = __builtin_amdgcn_mfma_f32_16x16x32_bf16(al, wf[jj][a][ks], acc[jj][a], 0, 0, 0);
                }
        }
        // prefetch XW for t+1 (only real rows; loads stay in flight across compute)
        const int tn = (t < Tt - 1) ? t + 1 : Tt - 1;
        if (q == 0) {
#pragma unroll
            for (int jj = 0; jj < 2; jj++)
#pragma unroll
                for (int a = 0; a < 4; a++) {
                    const int n = a * 128 + (w + 4 * jj) * 16 + col;
#pragma unroll
                    for (int r = 0; r < 2; r++)
                        nxt[jj][a][r] = XW[((b0 + r) * Tt + tn) * G4 + n];
                }
        }
        __syncthreads();   // all h reads done before h writes
        if (q == 0) {
#pragma unroll
            for (int jj = 0; jj < 2; jj++) {
                const int j = (w + 4 * jj) * 16 + col;
#pragma unroll
                for (int r = 0; r < 2; r++) {
                    const float gi = acc[jj][0][r], gf = acc[jj][1][r];
                    const float gg = acc[jj][2][r], go = acc[jj][3][r];
                    const float si = 1.f / (1.f + expf(-gi));
                    const float sf = 1.f / (1.f + expf(-gf));
                    const float so = 1.f / (1.f + expf(-go));
                    const float c = sf * cst[jj][r] + si * tanhf(gg);
                    cst[jj][r] = c;
                    const float hh = so * tanhf(c);
                    const u16 hi = f2bf(hh);
                    hHi[r * 136 + j] = hi;
                    hLo[r * 136 + j] = f2bf(hh - bfs(hi));
                    const long idx = ((b0 + r) * Tt + t) * OUT_ + j;
                    if (OBF16) ((u16*)hseq)[idx] = hi;
                    else       ((float*)hseq)[idx] = hh;
                }
            }
        }
        __syncthreads();   // h(t) visible before next step's reads
    }
}

// ---------------- attention pooling + FC
__global__ __launch_bounds__(64) void k_attn_fc(const float* __restrict__ h2,
                                                const float* __restrict__ attn_w,
                                                const float* __restrict__ attn_b,
                                                const float* __restrict__ fc_w,
                                                const float* __restrict__ fc_b,
                                                float* __restrict__ out) {
    const int b = blockIdx.x, t = threadIdx.x;
    __shared__ float aw[Tt];
    __shared__ float ctx[OUT_];
    const float* hb = h2 + (long)b * Tt * OUT_;
    float acc = 0.f;
    for (int d = 0; d < OUT_; d++) acc += hb[t * OUT_ + d] * attn_w[d];
    float sc = tanhf(acc + attn_b[0]);
    float m = sc;
#pragma unroll
    for (int o = 32; o > 0; o >>= 1) m = fmaxf(m, __shfl_xor(m, o));
    float ex = expf(sc - m);
    float sum = ex;
#pragma unroll
    for (int o = 32; o > 0; o >>= 1) sum += __shfl_xor(sum, o);
    aw[t] = ex / sum;
    __syncthreads();
    for (int d = t; d < OUT_; d += 64) {
        float c = 0.f;
        for (int tt = 0; tt < Tt; tt++) c += aw[tt] * hb[tt * OUT_ + d];
        ctx[d] = c;
    }
    __syncthreads();
    if (t < NCLS) {
        float o = fc_b[t];
        for (int d = 0; d < OUT_; d++) o += ctx[d] * fc_w[t * OUT_ + d];
        out[b * NCLS + t] = o;
    }
}

extern "C" void kernel_launch(void* const* d_in, const int* in_sizes, int n_in,
                              void* d_out, int out_size, void* d_ws, size_t ws_size,
                              hipStream_t stream) {
    const float* x          = (const float*)d_in[0];
    const int*   edge_index = (const int*)d_in[1];
    const float* gw[4]  = {(const float*)d_in[2], (const float*)d_in[6], (const float*)d_in[10], (const float*)d_in[14]};
    const float* gas[4] = {(const float*)d_in[3], (const float*)d_in[7], (const float*)d_in[11], (const float*)d_in[15]};
    const float* gad[4] = {(const float*)d_in[4], (const float*)d_in[8], (const float*)d_in[12], (const float*)d_in[16]};
    const float* gb[4]  = {(const float*)d_in[5], (const float*)d_in[9], (const float*)d_in[13], (const float*)d_in[17]};
    const float* wih0 = (const float*)d_in[18];
    const float* whh0 = (const float*)d_in[19];
    const float* bih0 = (const float*)d_in[20];
    const float* bhh0 = (const float*)d_in[21];
    const float* wih1 = (const float*)d_in[22];
    const float* whh1 = (const float*)d_in[23];
    const float* bih1 = (const float*)d_in[24];
    const float* bhh1 = (const float*)d_in[25];
    const float* attn_w = (const float*)d_in[26];
    const float* attn_b = (const float*)d_in[27];
    const float* fc_w   = (const float*)d_in[28];
    const float* fc_b   = (const float*)d_in[29];
    float* out = (float*)d_out;
    char* p = (char*)d_ws;

    // Workspace (~158.2 MB; 176.2 MB proven OK in round 2)
    u16*   hbuf  = (u16*)(p + 0L);              // 71,303,168 B
    float* aux   = (float*)(p + 71303168L);     //  4,456,448 B
    float* XW0   = (float*)(p + 75759616L);     // 33,554,432 B
    float* XW1   = (float*)(p + 109314048L);    // 33,554,432 B
    float* h2s   = (float*)(p + 142868480L);    //  8,388,608 B
    u16*   h1s   = (u16*)(p + 151257088L);      //  4,194,304 B
    u16*   wih0b = (u16*)(p + 155451392L);      //  2,228,224 B
    u16*   wih1b = (u16*)(p + 157679616L);      //    131,072 B
    u16*   whh0b = (u16*)(p + 157810688L);      //    131,072 B
    u16*   whh1b = (u16*)(p + 157941760L);      //    131,072 B
    u16*   wt1   = (u16*)(p + 158072832L);      //     32,768 B (x3)
    u16*   wt2   = (u16*)(p + 158105600L);
    u16*   wt3   = (u16*)(p + 158138368L);
    int*   csr   = (int*)(p + 158171136L);      //      1,044 B

    k_setup<<<1, 1, 0, stream>>>(edge_index, csr);
    k_convert_t128<<<64, 256, 0, stream>>>(gw[1], wt1);
    k_convert_t128<<<64, 256, 0, stream>>>(gw[2], wt2);
    k_convert_t128<<<64, 256, 0, stream>>>(gw[3], wt3);
    k_convert<<<(512 * 2176 + 255) / 256, 256, 0, stream>>>(wih0, wih0b, 512L * 2176);
    k_convert<<<256, 256, 0, stream>>>(wih1, wih1b, 512L * 128);
    k_convert<<<256, 256, 0, stream>>>(whh0, whh0b, 512L * 128);
    k_convert<<<256, 256, 0, stream>>>(whh1, whh1b, 512L * 128);

    // GAT layer 0 projection (+fp32 attn dots) then attention
    k_l0<<<Mg / 16, 256, 0, stream>>>(x, gw[0], gas[0], gad[0], hbuf, aux);
    k_gat_attn<<<Gg / GPB, 256, 0, stream>>>(hbuf, aux, gb[0], csr, 1);
    // layers 1..3: in-place MFMA GEMM with fp32 dot epilogue, then attention
    k_gemm_gat<<<Mg / 128, 256, 0, stream>>>(hbuf, wt1, gas[1], gad[1], aux);
    k_gat_attn<<<Gg / GPB, 256, 0, stream>>>(hbuf, aux, gb[1], csr, 0);
    k_gemm_gat<<<Mg / 128, 256, 0, stream>>>(hbuf, wt2, gas[2], gad[2], aux);
    k_gat_attn<<<Gg / GPB, 256, 0, stream>>>(hbuf, aux, gb[2], csr, 1);
    k_gemm_gat<<<Mg / 128, 256, 0, stream>>>(hbuf, wt3, gas[3], gad[3], aux);
    k_gat_attn<<<Gg / GPB, 256, 0, stream>>>(hbuf, aux, gb[3], csr, 0);

    // LSTM layer 0: input GEMM (hbuf == lstm_in [16384,2176] bf16) + MFMA recurrence
    k_gemm_mfma<<<dim3(Gg / 128, 4), 256, 0, stream>>>(hbuf, wih0b, XW0, bih0, bhh0, LSTM_IN, G4);
    k_lstm_mfma<1><<<Bb / 2, 256, 0, stream>>>(XW0, whh0b, h1s);
    // LSTM layer 1
    k_gemm_mfma<<<dim3(Gg / 128, 4), 256, 0, stream>>>(h1s, wih1b, XW1, bih1, bhh1, OUT_, G4);
    k_lstm_mfma<0><<<Bb / 2, 256, 0, stream>>>(XW1, whh1b, h2s);

    k_attn_fc<<<Bb, 64, 0, stream>>>(h2s, attn_w, attn_b, fc_w, fc_b, out);
}